// Round 4
// baseline (104.694 us; speedup 1.0000x reference)
//
#include <hip/hip_runtime.h>
#include <type_traits>

// AttentionLayer: out = softmax(Q @ V^T) @ V ; B=4, SQ=SKV=4096, D=64, fp32.
//
// R17: VALU-diet on R16 (bit-exact: addressing + unroll only, NO FP changes).
// LESSON (R14/R15): absmax sits EXACTLY at tolerance 0.03125. S=8 failed
// twice -> zero numeric headroom; only bit-exact transforms admissible.
// S stays 4. Lazy rescale (al==1.0 exact skip) + PV/softmax pipeline +
// setprio kept from R16 (passed, bit-identical).
//
// R16 post-mortem: VALUBusy 53.8% @ 16 waves/CU => ~450 VALU instr/wave-iter,
// of which only ~120 are softmax math. The rest: per-iter LDS address
// recompute (dynamic lds[cur] defeats base+offset folding) and 64-bit DMA
// address formation. VALU+MFMA issue ~76% saturated => cut instruction COUNT.
// R17 changes:
//  1. K-loop unrolled x2 with compile-time BUF => every ds_read_b128 is
//     one base VGPR + offset: imm (two per-lane bases: ch0=quad^c7, ch1=ch0^4,
//     computed once; all offsets < 32KB).
//  2. DMA via 4 persistent pointers bumped by constant strides (8 VALU/iter)
//     instead of full address recompute.
// R12 lesson: no __threadfence per block (L2 writeback storm, 7x).

#define NB   4
#define SQ   4096
#define SKV  4096
#define DH   64
#define L2E  1.44269504088896340736f

typedef _Float16 half8 __attribute__((ext_vector_type(8)));
typedef _Float16 half4 __attribute__((ext_vector_type(4)));
typedef _Float16 half2v __attribute__((ext_vector_type(2)));
typedef float f32x4 __attribute__((ext_vector_type(4)));
typedef unsigned short u16;

#define MFMA16(a, b, c) __builtin_amdgcn_mfma_f32_16x16x16f16((a), (b), (c), 0, 0, 0)
#define MFMA32(a, b, c) __builtin_amdgcn_mfma_f32_16x16x32_f16((a), (b), (c), 0, 0, 0)

__device__ __forceinline__ u16 f2h(float f) {
  _Float16 h = (_Float16)f;
  return __builtin_bit_cast(u16, h);
}
__device__ __forceinline__ half2v pkrtz(float a, float b) {
  return __builtin_bit_cast(half2v, __builtin_amdgcn_cvt_pkrtz(a, b));
}
__device__ __forceinline__ float fmax3(float a, float b, float c) {
  return fmaxf(fmaxf(a, b), c);   // clang fuses to v_max3_f32
}

typedef __attribute__((address_space(1))) void gvoid;
typedef __attribute__((address_space(3))) void lvoid;
__device__ __forceinline__ void dma16(const u16* g, u16* l) {
  __builtin_amdgcn_global_load_lds((gvoid*)g, (lvoid*)l, 16, 0, 0);
}

// ---------------------------------------------------------------- prep ----
// V fp32 -> vh fp16 [b][j][d-chunks swizzled by j&7]
//        -> vt fp16 [b][d][per-64-tile: phys chunk h^(d&7), h=(kc2*4+quad),
//                    elem e: kv = kc2*32+(e>>2)*16+quad*4+(e&3)]
__global__ __launch_bounds__(256) void prep_kernel(
    const float* __restrict__ V, u16* __restrict__ vh, u16* __restrict__ vt) {
  __shared__ u16 ldsT[16 * 72];
  int blk = blockIdx.x;
  int b   = blk >> 8;
  int rem = blk & 255;
  int j0  = (rem >> 2) << 6;   // kv tile base
  int d0  = (rem & 3) << 4;    // d tile base
  int t   = threadIdx.x;
  int j   = t >> 2;            // 0..63
  int dc  = (t & 3) << 2;      // 0,4,8,12

  const float* src = V + ((size_t)(b * SKV) + j0 + j) * DH + d0 + dc;
  float4 v4 = *(const float4*)src;
  u16 h[4] = {f2h(v4.x), f2h(v4.y), f2h(v4.z), f2h(v4.w)};
  unsigned p0 = (unsigned)h[0] | ((unsigned)h[1] << 16);
  unsigned p1 = (unsigned)h[2] | ((unsigned)h[3] << 16);
  int dfull = d0 + dc;
  int physd = ((((dfull >> 3) ^ (j & 7)) << 3)) + (dfull & 7);
  *(uint2*)(vh + ((size_t)(b * SKV) + j0 + j) * DH + physd) = make_uint2(p0, p1);

#pragma unroll
  for (int k = 0; k < 4; ++k) ldsT[(dc + k) * 72 + j] = h[k];
  __syncthreads();

  int dl = t >> 4;             // 0..15
  int jc = (t & 15) << 2;      // 0..60 (4 consecutive kv)
  u16 tr[4];
#pragma unroll
  for (int k = 0; k < 4; ++k) tr[k] = ldsT[dl * 72 + jc + k];
  unsigned q0 = (unsigned)tr[0] | ((unsigned)tr[1] << 16);
  unsigned q1 = (unsigned)tr[2] | ((unsigned)tr[3] << 16);
  int d   = d0 + dl;
  int kc2 = jc >> 5;
  int g   = (jc >> 4) & 1;
  int qd  = (jc >> 2) & 3;
  int hp  = ((kc2 << 2) | qd) ^ (d & 7);
  *(uint2*)(vt + ((size_t)(b * DH) + d) * SKV + j0 + (hp << 3) + (g << 2)) =
      make_uint2(q0, q1);
}

// ---------------------------------------------------------------- attn ----
// grid NB*64*S blocks, 256 threads = 4 waves * 16 q-cols each (64 q/block).
__global__ __launch_bounds__(256, 4) void attn_kernel(
    const float* __restrict__ Q,
    const u16* __restrict__ vh,
    const u16* __restrict__ vt,
    u16* __restrict__ po,    // [NB*64*S][64 q][64 d] fp16 unnormalized O
    float* __restrict__ pm,  // [NB*64*S][64] running max (log2 domain)
    float* __restrict__ pl,  // [NB*64*S][64] running sum
    int S, int kvLen) {
  __shared__ __align__(16) u16 lds[2][2][4096];  // [buf][0=V,1=VT], 32 KB

  int blk  = blockIdx.x;
  int tile = blk / S;          // b*64 + qtile
  int s    = blk - tile * S;
  int b    = tile >> 6;
  int q0   = (tile & 63) << 6;
  int kv0  = s * kvLen;
  int t    = threadIdx.x;
  int wave = t >> 6;
  int lane = t & 63;
  int col  = lane & 15;
  int quad = lane >> 4;
  int qw   = q0 + (wave << 4);
  int c7   = col & 7;

  const u16* gv  = vh + (size_t)(b * SKV) * DH;
  const u16* gvt = vt + (size_t)(b * DH) * SKV;

  int r0 = t >> 3;             // DMA row 0..31 (second instr: +32)
  int c0 = (t & 7) << 3;       // DMA chunk elem offset
  int wb = wave << 9;          // wave-uniform LDS dest base (elems)

  // ---- Q fragment as B-operand (n=col=q, k=quad*8+j), log2e folded
  half8 qf[2];
#pragma unroll
  for (int kc = 0; kc < 2; ++kc) {
    const float* qp = Q + ((size_t)(b * SQ) + qw + col) * DH + kc * 32 + (quad << 3);
    float4 a0 = *(const float4*)qp;
    float4 a1 = *(const float4*)(qp + 4);
    half8 hq;
    hq[0] = (_Float16)(a0.x * L2E); hq[1] = (_Float16)(a0.y * L2E);
    hq[2] = (_Float16)(a0.z * L2E); hq[3] = (_Float16)(a0.w * L2E);
    hq[4] = (_Float16)(a1.x * L2E); hq[5] = (_Float16)(a1.y * L2E);
    hq[6] = (_Float16)(a1.z * L2E); hq[7] = (_Float16)(a1.w * L2E);
    qf[kc] = hq;
  }

  f32x4 o[4];                  // O^T frags: d = nf2*16+quad*4+r, q = col
#pragma unroll
  for (int nf = 0; nf < 4; ++nf) o[nf] = (f32x4){0.f, 0.f, 0.f, 0.f};
  float m_r = -1e30f, l_r = 0.f;

  half4 pf[4];                 // P^T frags of CURRENT tile (consumed next iter)
  half8 vr[8];                 // staged VT frags of CURRENT tile (next iter's PV)

  // ---- per-lane LDS read bases (bytes), computed ONCE.
  //      read(kc, nf): aKC + BUF*16384 (+8192 for VT) + nf*2048  [all imm]
  int ch0 = quad ^ c7;
  int ch1 = ch0 ^ 4;
  const char* Lb = (const char*)&lds[0][0][0];
  const char* a0p = Lb + (col << 7) + (ch0 << 4);
  const char* a1p = Lb + (col << 7) + (ch1 << 4);

  // ---- persistent DMA source pointers, bumped by constant strides
  const u16* pvh  = gv + ((size_t)(kv0 + r0) << 6) + c0;
  const u16* pvh2 = pvh + 2048;           // +32 kv rows
  const u16* pvt  = gvt + (size_t)r0 * SKV + kv0 + c0;
  const u16* pvt2 = pvt + (size_t)32 * SKV;

  // prologue: DMA tile 0 into buf 0 (drained by first barrier)
  dma16(pvh,  &lds[0][0][0] + wb);
  dma16(pvh2, &lds[0][0][0] + 2048 + wb);
  dma16(pvt,  &lds[0][1][0] + wb);
  dma16(pvt2, &lds[0][1][0] + 2048 + wb);
  pvh += 4096; pvh2 += 4096; pvt += 64; pvt2 += 64;

  int nIter = kvLen >> 6;      // 16 at S=4 (always even)

  auto body = [&](auto BUFC, int it_) {
    constexpr int BUF = decltype(BUFC)::value;
    constexpr int BO  = BUF * 16384;       // buffer byte offset
    __syncthreads();           // drains prior DMA (vmcnt(0)) + buf handoff

    if (it_ + 1 < nIter) {     // DMA next tile into the OTHER buffer
      dma16(pvh,  &lds[BUF ^ 1][0][0] + wb);
      dma16(pvh2, &lds[BUF ^ 1][0][0] + 2048 + wb);
      dma16(pvt,  &lds[BUF ^ 1][1][0] + wb);
      dma16(pvt2, &lds[BUF ^ 1][1][0] + 2048 + wb);
    }
    pvh += 4096; pvh2 += 4096; pvt += 64; pvt2 += 64;

    // ---- S^T = V @ Q^T : sf[nf] covers kv = nf*16 + quad*4 + r
    f32x4 sf[4];
#pragma unroll
    for (int nf = 0; nf < 4; ++nf) sf[nf] = (f32x4){0.f, 0.f, 0.f, 0.f};
    __builtin_amdgcn_s_setprio(1);
#pragma unroll
    for (int nf = 0; nf < 4; ++nf) {
      half8 av0 = *(const half8*)(a0p + BO + nf * 2048);
      sf[nf] = MFMA32(av0, qf[0], sf[nf]);
      half8 av1 = *(const half8*)(a1p + BO + nf * 2048);
      sf[nf] = MFMA32(av1, qf[1], sf[nf]);
    }
    __builtin_amdgcn_s_setprio(0);

    // ---- PV(t-1) from staged regs: overlaps softmax(t) in the schedule.
    //      Bit-exact reorder (o-register dependence keeps accumulation order).
    if (it_ > 0) {
      __builtin_amdgcn_s_setprio(1);
#pragma unroll
      for (int kc2 = 0; kc2 < 2; ++kc2) {
#pragma unroll
        for (int nf2 = 0; nf2 < 4; ++nf2) {
          half8 w8 = vr[kc2 * 4 + nf2];
          half4 wlo = __builtin_shufflevector(w8, w8, 0, 1, 2, 3);
          half4 whi = __builtin_shufflevector(w8, w8, 4, 5, 6, 7);
          o[nf2] = MFMA16(wlo, pf[kc2 * 2], o[nf2]);
          o[nf2] = MFMA16(whi, pf[kc2 * 2 + 1], o[nf2]);
        }
      }
      __builtin_amdgcn_s_setprio(0);
    }

    // ---- online softmax(t): exact values; lazy (bit-exact) rescale.
    {
      float t0 = fmax3(sf[0][0], sf[0][1], sf[0][2]);
      float t1 = fmax3(sf[0][3], sf[1][0], sf[1][1]);
      float t2 = fmax3(sf[1][2], sf[1][3], sf[2][0]);
      float t3 = fmax3(sf[2][1], sf[2][2], sf[2][3]);
      float t4 = fmax3(sf[3][0], sf[3][1], sf[3][2]);
      float t5 = fmax3(t0, t1, sf[3][3]);
      float tm = fmax3(t2, t3, t4);
      tm = fmaxf(tm, t5);
      tm = fmaxf(tm, __shfl_xor(tm, 16, 64));
      tm = fmaxf(tm, __shfl_xor(tm, 32, 64));
      float mn = fmaxf(m_r, tm);
      float al = 1.0f;
      if (!__all(mn == m_r)) {   // skip => al==1.0 exactly: o*1, l*1 exact
        al = exp2f(m_r - mn);
        m_r = mn;
#pragma unroll
        for (int nf = 0; nf < 4; ++nf)
#pragma unroll
          for (int r = 0; r < 4; ++r) o[nf][r] *= al;
      }
      float rs = 0.f;
#pragma unroll
      for (int nf = 0; nf < 4; ++nf) {
        float p0 = exp2f(sf[nf][0] - mn);
        float p1 = exp2f(sf[nf][1] - mn);
        float p2 = exp2f(sf[nf][2] - mn);
        float p3 = exp2f(sf[nf][3] - mn);
        rs += (p0 + p1) + (p2 + p3);
        half2v lo = pkrtz(p0, p1);
        half2v hi = pkrtz(p2, p3);
        pf[nf] = __builtin_shufflevector(lo, hi, 0, 1, 2, 3);
      }
      l_r = l_r * al + rs;
    }

    // ---- stage VT(t) into regs for next iter's PV
#pragma unroll
    for (int nf2 = 0; nf2 < 4; ++nf2) {
      vr[nf2]     = *(const half8*)(a0p + BO + 8192 + nf2 * 2048);
      vr[4 + nf2] = *(const half8*)(a1p + BO + 8192 + nf2 * 2048);
    }
  };

  for (int it = 0; it < nIter; it += 2) {
    body(std::integral_constant<int, 0>{}, it);
    body(std::integral_constant<int, 1>{}, it + 1);
  }

  // ---- drain: PV for the last tile
  __builtin_amdgcn_s_setprio(1);
#pragma unroll
  for (int kc2 = 0; kc2 < 2; ++kc2) {
#pragma unroll
    for (int nf2 = 0; nf2 < 4; ++nf2) {
      half8 w8 = vr[kc2 * 4 + nf2];
      half4 wlo = __builtin_shufflevector(w8, w8, 0, 1, 2, 3);
      half4 whi = __builtin_shufflevector(w8, w8, 4, 5, 6, 7);
      o[nf2] = MFMA16(wlo, pf[kc2 * 2], o[nf2]);
      o[nf2] = MFMA16(whi, pf[kc2 * 2 + 1], o[nf2]);
    }
  }
  __builtin_amdgcn_s_setprio(0);

  // ---- epilogue: l reduce across quads, pm/pl, transpose O^T -> po[q][d]
  l_r += __shfl_xor(l_r, 16, 64);
  l_r += __shfl_xor(l_r, 32, 64);
  int pidx = tile * S + s;
  if (quad == 0) {
    pm[(size_t)pidx * 64 + (wave << 4) + col] = m_r;
    pl[(size_t)pidx * 64 + (wave << 4) + col] = l_r;
  }

  __syncthreads();             // tile buffers free; reuse as [64 q][72]
  u16* tp = &lds[0][0][0];
  {
    int qrow = (wave << 4) + col;
#pragma unroll
    for (int nf2 = 0; nf2 < 4; ++nf2) {
#pragma unroll
      for (int r2 = 0; r2 < 4; r2 += 2) {
        unsigned pk = (unsigned)f2h(o[nf2][r2]) |
                      ((unsigned)f2h(o[nf2][r2 + 1]) << 16);
        int d = nf2 * 16 + (quad << 2) + r2;
        *(unsigned*)(tp + qrow * 72 + d) = pk;
      }
    }
  }
  __syncthreads();
  {
    u16* pob = po + (size_t)pidx * 64 * 64;
    int q = t >> 2, hc = (t & 3) << 4;
    uint4 x0 = *(const uint4*)(tp + q * 72 + hc);
    uint4 x1 = *(const uint4*)(tp + q * 72 + hc + 8);
    *(uint4*)(pob + q * 64 + hc)     = x0;
    *(uint4*)(pob + q * 64 + hc + 8) = x1;
  }
}

// ------------------------------------------------------------- combine ----
// grid NB*SQ/32 blocks, 256 threads; thread = (q row, 8-d chunk).
// Statically unrolled (S <= 8, predicated) so mv/lv/w stay in registers;
// iteration order identical to the dynamic loop -> bit-identical at S=4.
__global__ __launch_bounds__(256) void combine_kernel(
    const u16* __restrict__ po,
    const float* __restrict__ pm,
    const float* __restrict__ pl,
    float* __restrict__ out, int S) {
  int t    = threadIdx.x;
  int rowg = blockIdx.x * 32 + (t >> 3);   // global q row
  int tile = rowg >> 6;
  int row  = rowg & 63;
  int dc   = (t & 7) << 3;

  float mv[8], lv[8];
  float M = -1e30f;
#pragma unroll
  for (int s = 0; s < 8; ++s) {
    if (s < S) {
      mv[s] = pm[(size_t)(tile * S + s) * 64 + row];
      lv[s] = pl[(size_t)(tile * S + s) * 64 + row];
      M = fmaxf(M, mv[s]);
    }
  }
  float L = 0.f, w[8];
#pragma unroll
  for (int s = 0; s < 8; ++s) {
    if (s < S) {
      w[s] = exp2f(mv[s] - M);
      L += lv[s] * w[s];
    }
  }
  float acc[8] = {0.f, 0.f, 0.f, 0.f, 0.f, 0.f, 0.f, 0.f};
#pragma unroll
  for (int s = 0; s < 8; ++s) {
    if (s < S) {
      const u16* p = po + (size_t)(tile * S + s) * 4096 + row * 64 + dc;
      uint4 raw = *(const uint4*)p;
      half8 x = __builtin_bit_cast(half8, raw);
#pragma unroll
      for (int k = 0; k < 8; ++k) acc[k] += w[s] * (float)x[k];
    }
  }
  float invL = 1.0f / L;
  float* op = out + (size_t)rowg * 64 + dc;
  f32x4 o0 = (f32x4){acc[0], acc[1], acc[2], acc[3]};
  f32x4 o1 = (f32x4){acc[4], acc[5], acc[6], acc[7]};
  *(f32x4*)op       = o0 * invL;
  *(f32x4*)(op + 4) = o1 * invL;
}

// -------------------------------------------------------------- launch ----
extern "C" void kernel_launch(void* const* d_in, const int* in_sizes, int n_in,
                              void* d_out, int out_size, void* d_ws, size_t ws_size,
                              hipStream_t stream) {
  const float* Q = (const float*)d_in[0];
  const float* V = (const float*)d_in[1];
  float* out = (float*)d_out;

  const size_t convBytes = (size_t)2 * NB * SKV * DH * 2;  // vh+vt = 4 MB
  auto partBytes = [](int S) {
    return (size_t)NB * 64 * S * ((size_t)64 * 64 * 2 + 64 * 8);
  };
  // S pinned to 4: S=8 exceeded the absmax tolerance twice (R14/R15) —
  // the error budget is exactly exhausted at S=4. Do not raise.
  int S = 4;
  while (S > 1 && ws_size < convBytes + partBytes(S)) S >>= 1;
  int kvLen = SKV / S;

  u16* vh = (u16*)d_ws;
  u16* vt = vh + (size_t)NB * SKV * DH;
  u16* po = vt + (size_t)NB * SKV * DH;
  float* pm = (float*)(po + (size_t)NB * 64 * S * 64 * 64);
  float* pl = pm + (size_t)NB * 64 * S * 64;

  prep_kernel<<<NB * 256, 256, 0, stream>>>(V, vh, vt);
  attn_kernel<<<NB * 64 * S, 256, 0, stream>>>(Q, vh, vt, po, pm, pl, S, kvLen);
  combine_kernel<<<NB * SQ / 32, 256, 0, stream>>>(po, pm, pl, out, S);
}